// Round 1
// baseline (481.166 us; speedup 1.0000x reference)
//
#include <hip/hip_runtime.h>
#include <hip/hip_bf16.h>
#include <stdint.h>

// CrossAttention: out = softmax((x@Wq)(ctx@Wk)^T * scale) @ (ctx@Wv) @ Wo + bo
// B=16, NQ=4096, NK=77, QD=512, CD=768, H=8, DH=64, INNER=512
//
// Pipeline (round 0, correctness-first):
//   wt_conv x4 : W[K][N] f32 -> Wt[N][K] bf16 (ws)
//   gemm     : K = ctx @ Wk  -> bf16 [1232][512]   (BM=32 tiles for parallelism)
//   gemm     : V = ctx @ Wv  -> bf16 [1232][512]
//   gemm     : Q = x @ Wq    -> f32  [65536][512]  (kept f32 for accuracy)
//   attn     : in-place Q -> attention-out (f32), per (b,h,qtile) block
//   gemm     : out = AO @ Wo + bo -> f32 d_out

typedef __attribute__((ext_vector_type(8))) short bf16x8;
typedef __attribute__((ext_vector_type(4))) float f32x4;
typedef __attribute__((ext_vector_type(4))) short short4v;
typedef __attribute__((ext_vector_type(4))) float float4v;

#define DEVINL __device__ __forceinline__

DEVINL short f2bf(float f) {
  unsigned u = __builtin_bit_cast(unsigned, f);
  unsigned r = (u + 0x7FFFu + ((u >> 16) & 1u)) >> 16;  // RNE
  return (short)(unsigned short)r;
}

// ---------------- weight transpose+convert: W[K][N] f32 -> Wt[N][K] bf16 ----
__global__ __launch_bounds__(256) void wt_conv(const float* __restrict__ W,
                                               short* __restrict__ Wt,
                                               int K, int N) {
  __shared__ short Tl[64][65];
  const int kt = blockIdx.y * 64, nt = blockIdx.x * 64;
#pragma unroll
  for (int i = 0; i < 16; ++i) {
    int idx = threadIdx.x + i * 256;
    int r = idx >> 6, c = idx & 63;
    Tl[c][r] = f2bf(W[(size_t)(kt + r) * N + nt + c]);
  }
  __syncthreads();
#pragma unroll
  for (int i = 0; i < 16; ++i) {
    int idx = threadIdx.x + i * 256;
    int r = idx >> 6, c = idx & 63;
    Wt[(size_t)(nt + r) * K + kt + c] = Tl[r][c];
  }
}

// ---------------- generic bf16 MFMA GEMM: C[M][512] = A[M][K] @ Bt[512][K]^T
// AT: float (convert on stage) or short (bf16 pass-through)
// OUT: 0 = bf16 store, 1 = f32 store, 2 = f32 + bias
// MF: m-fragments per wave; tile = (32*MF) x 128, 4 waves (2x2), BK=32
template <typename AT, int OUT, int MF>
__global__ __launch_bounds__(256) void gemm_k(const AT* __restrict__ A,
                                              const short* __restrict__ Bt,
                                              void* __restrict__ Cv,
                                              const float* __restrict__ bias,
                                              int M, int K) {
  constexpr int BM = 32 * MF;
  __shared__ short Al[BM][40];   // stride 40 shorts (80B) -> 2-way banks max
  __shared__ short Bl[128][40];

  const int tid = threadIdx.x;
  const int lane = tid & 63, wid = tid >> 6;
  const int wm = wid >> 1, wn = wid & 1;
  const int half = lane >> 4, l16 = lane & 15;
  const int m0 = blockIdx.y * BM, n0 = blockIdx.x * 128;

  f32x4 acc[MF][4] = {};

  for (int k0 = 0; k0 < K; k0 += 32) {
    // ---- stage A tile [BM][32] ----
    if constexpr (sizeof(AT) == 4) {
      for (int idx = tid; idx < BM * 8; idx += 256) {
        int row = idx >> 3, kq = idx & 7;
        float4v v = {};
        if (m0 + row < M)
          v = *(const float4v*)(A + (size_t)(m0 + row) * K + k0 + kq * 4);
        short4v s = {f2bf(v[0]), f2bf(v[1]), f2bf(v[2]), f2bf(v[3])};
        *(short4v*)&Al[row][kq * 4] = s;
      }
    } else {
      for (int idx = tid; idx < BM * 4; idx += 256) {
        int row = idx >> 2, kq = idx & 3;
        bf16x8 v = {};
        if (m0 + row < M)
          v = *(const bf16x8*)(A + (size_t)(m0 + row) * K + k0 + kq * 8);
        *(bf16x8*)&Al[row][kq * 8] = v;
      }
    }
    // ---- stage B tile: Bt rows n0..n0+128, k0..k0+32 ----
    for (int idx = tid; idx < 512; idx += 256) {
      int row = idx >> 2, kq = idx & 3;
      *(bf16x8*)&Bl[row][kq * 8] =
          *(const bf16x8*)(Bt + (size_t)(n0 + row) * K + k0 + kq * 8);
    }
    __syncthreads();

    bf16x8 a[MF], bfr[4];
#pragma unroll
    for (int m = 0; m < MF; ++m)
      a[m] = *(bf16x8*)&Al[wm * MF * 16 + m * 16 + l16][half * 8];
#pragma unroll
    for (int n = 0; n < 4; ++n)
      bfr[n] = *(bf16x8*)&Bl[wn * 64 + n * 16 + l16][half * 8];
#pragma unroll
    for (int m = 0; m < MF; ++m)
#pragma unroll
      for (int n = 0; n < 4; ++n)
        acc[m][n] = __builtin_amdgcn_mfma_f32_16x16x32_bf16(a[m], bfr[n],
                                                            acc[m][n], 0, 0, 0);
    __syncthreads();
  }

  // ---- epilogue ----
#pragma unroll
  for (int m = 0; m < MF; ++m) {
#pragma unroll
    for (int n = 0; n < 4; ++n) {
      int col = n0 + wn * 64 + n * 16 + l16;
      int rowb = m0 + wm * MF * 16 + m * 16 + half * 4;
      float badd = (OUT == 2) ? bias[col] : 0.0f;
#pragma unroll
      for (int r = 0; r < 4; ++r) {
        int row = rowb + r;
        if (row < M) {
          if constexpr (OUT == 0)
            ((short*)Cv)[(size_t)row * 512 + col] = f2bf(acc[m][n][r]);
          else
            ((float*)Cv)[(size_t)row * 512 + col] = acc[m][n][r] + badd;
        }
      }
    }
  }
}

// ---------------- fused attention per (qtile, h, b) ----------------
// Qf: f32 [16*4096][512] in/out (in-place h-slice overwrite)
// Kb/Vb: bf16 [16*77][512], col = h*64 + d
__global__ __launch_bounds__(256) void attn_k(const short* __restrict__ Kb,
                                              const short* __restrict__ Vb,
                                              float* __restrict__ Qf) {
  __shared__ short Vt[64][104];       // V^T [d][key], keys padded to 96 used
  __shared__ short Pl[4][16][104];    // per-wave P [q][key]

  const int tid = threadIdx.x;
  const int lane = tid & 63, wid = tid >> 6;
  const int half = lane >> 4, l16 = lane & 15;
  const int qt = blockIdx.x, h = blockIdx.y, b = blockIdx.z;
  const size_t kvbase = ((size_t)b * 77) * 512 + h * 64;

  // stage V^T (bf16), zero-pad keys 77..103
  for (int i = tid; i < 77 * 32; i += 256) {
    int key = i >> 5, dp = (i & 31) * 2;
    int w = *(const int*)(Vb + kvbase + (size_t)key * 512 + dp);
    Vt[dp][key] = (short)(w & 0xffff);
    Vt[dp + 1][key] = (short)((unsigned)w >> 16);
  }
  for (int i = tid; i < 64 * 27; i += 256) {
    int d = i / 27, key = 77 + i % 27;
    Vt[d][key] = 0;
  }
  {  // zero own wave's P pad, keys 80..95
    short4v z = {};
    *(short4v*)&Pl[wid][l16][80 + half * 4] = z;
  }
  __syncthreads();

  const size_t qrow = (size_t)b * 4096 + qt * 64 + wid * 16 + l16;
  const float* qp = Qf + qrow * 512 + h * 64;

  // Q fragment (B operand of sim^T = K . Q^T): col=q=l16, k=d
  bf16x8 qfr[2];
#pragma unroll
  for (int ks = 0; ks < 2; ++ks) {
    float4v q0 = *(const float4v*)(qp + ks * 32 + half * 8);
    float4v q1 = *(const float4v*)(qp + ks * 32 + half * 8 + 4);
    bf16x8 t;
#pragma unroll
    for (int j = 0; j < 4; ++j) { t[j] = f2bf(q0[j]); t[4 + j] = f2bf(q1[j]); }
    qfr[ks] = t;
  }

  // sim^T tiles: 5 frags of 16 keys x 16 q
  f32x4 c[5] = {};
#pragma unroll
  for (int f = 0; f < 5; ++f) {
    int key = f * 16 + l16;
#pragma unroll
    for (int ks = 0; ks < 2; ++ks) {
      bf16x8 a = {};
      if (key < 77)
        a = *(const bf16x8*)(Kb + kvbase + (size_t)key * 512 + ks * 32 + half * 8);
      c[f] = __builtin_amdgcn_mfma_f32_16x16x32_bf16(a, qfr[ks], c[f], 0, 0, 0);
    }
  }

  // scale + mask + softmax over keys (rows of sim^T)
  float pv[5][4];
  float mx = -1e30f;
#pragma unroll
  for (int f = 0; f < 5; ++f)
#pragma unroll
    for (int r = 0; r < 4; ++r) {
      int key = f * 16 + half * 4 + r;
      float v = c[f][r] * 0.125f;
      if (key >= 77) v = -1e30f;
      pv[f][r] = v;
      mx = fmaxf(mx, v);
    }
  mx = fmaxf(mx, __shfl_xor(mx, 16));
  mx = fmaxf(mx, __shfl_xor(mx, 32));
  float sum = 0.0f;
#pragma unroll
  for (int f = 0; f < 5; ++f)
#pragma unroll
    for (int r = 0; r < 4; ++r) {
      float e = __expf(pv[f][r] - mx);
      pv[f][r] = e;
      sum += e;
    }
  sum += __shfl_xor(sum, 16);
  sum += __shfl_xor(sum, 32);

  // write P (unnormalized, bf16) to LDS: P[q=l16][key]
#pragma unroll
  for (int f = 0; f < 5; ++f) {
    short4v s = {f2bf(pv[f][0]), f2bf(pv[f][1]), f2bf(pv[f][2]), f2bf(pv[f][3])};
    *(short4v*)&Pl[wid][l16][f * 16 + half * 4] = s;
  }
  __syncthreads();

  // out^T = V^T . P^T : A from Vt, B from Pl (col=q=l16, k=key)
  bf16x8 pb[3];
#pragma unroll
  for (int ks = 0; ks < 3; ++ks)
    pb[ks] = *(const bf16x8*)&Pl[wid][l16][ks * 32 + half * 8];
  f32x4 o[4] = {};
#pragma unroll
  for (int mt = 0; mt < 4; ++mt)
#pragma unroll
    for (int ks = 0; ks < 3; ++ks) {
      bf16x8 a = *(const bf16x8*)&Vt[mt * 16 + l16][ks * 32 + half * 8];
      o[mt] = __builtin_amdgcn_mfma_f32_16x16x32_bf16(a, pb[ks], o[mt], 0, 0, 0);
    }

  const float inv = 1.0f / sum;
  float* op = Qf + qrow * 512 + h * 64;
#pragma unroll
  for (int mt = 0; mt < 4; ++mt) {
    float4v s = {o[mt][0] * inv, o[mt][1] * inv, o[mt][2] * inv, o[mt][3] * inv};
    *(float4v*)(op + mt * 16 + half * 4) = s;
  }
}

extern "C" void kernel_launch(void* const* d_in, const int* in_sizes, int n_in,
                              void* d_out, int out_size, void* d_ws, size_t ws_size,
                              hipStream_t stream) {
  const float* x   = (const float*)d_in[0];
  const float* ctx = (const float*)d_in[1];
  const float* Wq  = (const float*)d_in[2];
  const float* Wk  = (const float*)d_in[3];
  const float* Wv  = (const float*)d_in[4];
  const float* Wo  = (const float*)d_in[5];
  const float* bo  = (const float*)d_in[6];
  float* out = (float*)d_out;

  char* ws = (char*)d_ws;
  short* wqt = (short*)(ws);                               // 512*512 bf16
  short* wkt = (short*)(ws + 524288);                      // 768*512 bf16
  short* wvt = (short*)(ws + 524288 + 786432);             // 768*512 bf16
  short* wot = (short*)(ws + 524288 + 2 * 786432);         // 512*512 bf16
  short* Kb  = (short*)(ws + 2621440);                     // 1232*512 bf16
  short* Vb  = (short*)(ws + 2621440 + 1261568);           // 1232*512 bf16
  float* Qf  = (float*)(ws + 2621440 + 2 * 1261568);       // 65536*512 f32

  // weights -> bf16 transposed [N][K]
  wt_conv<<<dim3(8, 8), 256, 0, stream>>>(Wq, wqt, 512, 512);
  wt_conv<<<dim3(8, 12), 256, 0, stream>>>(Wk, wkt, 768, 512);
  wt_conv<<<dim3(8, 12), 256, 0, stream>>>(Wv, wvt, 768, 512);
  wt_conv<<<dim3(8, 8), 256, 0, stream>>>(Wo, wot, 512, 512);

  // K/V projections (M=1232, K=768) -> bf16
  gemm_k<float, 0, 1><<<dim3(4, 39), 256, 0, stream>>>(ctx, wkt, Kb, nullptr, 1232, 768);
  gemm_k<float, 0, 1><<<dim3(4, 39), 256, 0, stream>>>(ctx, wvt, Vb, nullptr, 1232, 768);

  // Q projection (M=65536, K=512) -> f32
  gemm_k<float, 1, 4><<<dim3(4, 512), 256, 0, stream>>>(x, wqt, Qf, nullptr, 65536, 512);

  // attention, in-place on Qf
  attn_k<<<dim3(64, 8, 16), 256, 0, stream>>>(Kb, Vb, Qf);

  // output projection + bias (M=65536, K=512) -> f32 d_out
  gemm_k<float, 2, 4><<<dim3(4, 512), 256, 0, stream>>>(Qf, wot, out, bo, 65536, 512);
}

// Round 2
// 304.703 us; speedup vs baseline: 1.5791x; 1.5791x over previous
//
#include <hip/hip_runtime.h>
#include <hip/hip_bf16.h>
#include <stdint.h>

// CrossAttention: out = softmax((x@Wq)(ctx@Wk)^T * scale) @ (ctx@Wv) @ Wo + bo
// B=16, NQ=4096, NK=77, QD=512, CD=768, H=8, DH=64, INNER=512
//
// Round 1: bf16 intermediates end-to-end + m97-structure GEMM
// (128x128 tile, BK=64, global_load_lds width-16, 2-barrier loop) for the
// two 65536x512x512 projections. K/V proj + attention keep round-0 shape.

typedef __attribute__((ext_vector_type(8))) short bf16x8;
typedef __attribute__((ext_vector_type(4))) float f32x4;
typedef __attribute__((ext_vector_type(4))) short short4v;
typedef __attribute__((ext_vector_type(4))) float float4v;

#define DEVINL __device__ __forceinline__

DEVINL short f2bf(float f) {
  unsigned u = __builtin_bit_cast(unsigned, f);
  unsigned r = (u + 0x7FFFu + ((u >> 16) & 1u)) >> 16;  // RNE
  return (short)(unsigned short)r;
}

#define GLDS16(gp, sp)                                                \
  __builtin_amdgcn_global_load_lds(                                   \
      (const __attribute__((address_space(1))) void*)(gp),            \
      (__attribute__((address_space(3))) void*)(sp), 16, 0, 0)

// ---------------- f32 -> bf16 vectorized convert (8 elems/thread/iter) ----
__global__ __launch_bounds__(256) void conv_bf16(const float* __restrict__ in,
                                                 short* __restrict__ out,
                                                 size_t n8) {
  size_t i = (size_t)blockIdx.x * 256 + threadIdx.x;
  const size_t stride = (size_t)gridDim.x * 256;
  for (; i < n8; i += stride) {
    float4v a = *(const float4v*)(in + i * 8);
    float4v b = *(const float4v*)(in + i * 8 + 4);
    bf16x8 o = {f2bf(a[0]), f2bf(a[1]), f2bf(a[2]), f2bf(a[3]),
                f2bf(b[0]), f2bf(b[1]), f2bf(b[2]), f2bf(b[3])};
    *(bf16x8*)(out + i * 8) = o;
  }
}

// ---------------- weight transpose+convert: W[K][N] f32 -> Wt[N][K] bf16 ----
__global__ __launch_bounds__(256) void wt_conv(const float* __restrict__ W,
                                               short* __restrict__ Wt,
                                               int K, int N) {
  __shared__ short Tl[64][65];
  const int kt = blockIdx.y * 64, nt = blockIdx.x * 64;
#pragma unroll
  for (int i = 0; i < 16; ++i) {
    int idx = threadIdx.x + i * 256;
    int r = idx >> 6, c = idx & 63;
    Tl[c][r] = f2bf(W[(size_t)(kt + r) * N + nt + c]);
  }
  __syncthreads();
#pragma unroll
  for (int i = 0; i < 16; ++i) {
    int idx = threadIdx.x + i * 256;
    int r = idx >> 6, c = idx & 63;
    Wt[(size_t)(nt + r) * K + kt + c] = Tl[r][c];
  }
}

// ---------------- m97-structure GEMM: C[M][N] = A[M][K] @ Bt[N][K]^T -------
// A, Bt bf16 row-major. 128x128 tile, BK=64, 4 waves (2x2), each wave 64x64.
// Requires M%128==0, N%128==0, K%64==0.
// OUT: 0 = bf16 store, 1 = f32 store, 2 = f32 + bias
template <int OUT>
__global__ __launch_bounds__(256) void gemm_m97(const short* __restrict__ A,
                                                const short* __restrict__ Bt,
                                                void* __restrict__ Cv,
                                                const float* __restrict__ bias,
                                                int M, int N, int K) {
  __shared__ short Al[128 * 64];  // 16 KB, row stride 64 shorts (128 B)
  __shared__ short Bl[128 * 64];  // 16 KB

  const int tid = threadIdx.x;
  const int lane = tid & 63, w = tid >> 6;
  const int wm = w >> 1, wn = w & 1;
  const int half = lane >> 4, l16 = lane & 15;
  const int m0 = blockIdx.y * 128, n0 = blockIdx.x * 128;

  const int lr = lane >> 3;            // 0..7: row within 8-row pass chunk
  const int lc = (lane & 7) * 8;       // bf16 col offset within BK=64

  f32x4 acc[4][4] = {};

  for (int k0 = 0; k0 < K; k0 += 64) {
    // ---- stage A[128][64] and B[128][64] via global_load_lds, linear LDS --
#pragma unroll
    for (int p = 0; p < 4; ++p) {
      const int row = w * 32 + p * 8;  // wave-uniform chunk base row
      GLDS16(A + (size_t)(m0 + row + lr) * K + k0 + lc, &Al[row * 64]);
      GLDS16(Bt + (size_t)(n0 + row + lr) * K + k0 + lc, &Bl[row * 64]);
    }
    __syncthreads();  // compiler emits vmcnt(0) drain before barrier

#pragma unroll
    for (int ks = 0; ks < 2; ++ks) {
      bf16x8 af[4], bfr[4];
#pragma unroll
      for (int m = 0; m < 4; ++m)
        af[m] = *(bf16x8*)&Al[(wm * 64 + m * 16 + l16) * 64 + ks * 32 + half * 8];
#pragma unroll
      for (int n = 0; n < 4; ++n)
        bfr[n] = *(bf16x8*)&Bl[(wn * 64 + n * 16 + l16) * 64 + ks * 32 + half * 8];
#pragma unroll
      for (int m = 0; m < 4; ++m)
#pragma unroll
        for (int n = 0; n < 4; ++n)
          acc[m][n] = __builtin_amdgcn_mfma_f32_16x16x32_bf16(af[m], bfr[n],
                                                              acc[m][n], 0, 0, 0);
    }
    __syncthreads();
  }

  // ---- epilogue: C/D layout col=lane&15, row=(lane>>4)*4+r ----
#pragma unroll
  for (int m = 0; m < 4; ++m) {
#pragma unroll
    for (int n = 0; n < 4; ++n) {
      const int col = n0 + wn * 64 + n * 16 + l16;
      const int rowb = m0 + wm * 64 + m * 16 + half * 4;
      const float badd = (OUT == 2) ? bias[col] : 0.0f;
#pragma unroll
      for (int r = 0; r < 4; ++r) {
        if constexpr (OUT == 0)
          ((short*)Cv)[(size_t)(rowb + r) * N + col] = f2bf(acc[m][n][r]);
        else
          ((float*)Cv)[(size_t)(rowb + r) * N + col] = acc[m][n][r] + badd;
      }
    }
  }
}

// ---------------- small GEMM for K/V proj: C[M][512] = A[M][K] @ Bt[512][K]^T
// A bf16, out bf16. tile 32x128, 4 waves (2x2), BK=32. Handles M edge.
__global__ __launch_bounds__(256) void gemm_small(const short* __restrict__ A,
                                                  const short* __restrict__ Bt,
                                                  short* __restrict__ C,
                                                  int M, int K) {
  __shared__ short Al[32][40];
  __shared__ short Bl[128][40];

  const int tid = threadIdx.x;
  const int lane = tid & 63, wid = tid >> 6;
  const int wm = wid >> 1, wn = wid & 1;
  const int half = lane >> 4, l16 = lane & 15;
  const int m0 = blockIdx.y * 32, n0 = blockIdx.x * 128;

  f32x4 acc[4] = {};

  for (int k0 = 0; k0 < K; k0 += 32) {
    for (int idx = tid; idx < 32 * 4; idx += 256) {
      int row = idx >> 2, kq = idx & 3;
      bf16x8 v = {};
      if (m0 + row < M)
        v = *(const bf16x8*)(A + (size_t)(m0 + row) * K + k0 + kq * 8);
      *(bf16x8*)&Al[row][kq * 8] = v;
    }
    for (int idx = tid; idx < 512; idx += 256) {
      int row = idx >> 2, kq = idx & 3;
      *(bf16x8*)&Bl[row][kq * 8] =
          *(const bf16x8*)(Bt + (size_t)(n0 + row) * K + k0 + kq * 8);
    }
    __syncthreads();

    bf16x8 a = *(bf16x8*)&Al[wm * 16 + l16][half * 8];
#pragma unroll
    for (int n = 0; n < 4; ++n) {
      bf16x8 b = *(bf16x8*)&Bl[wn * 64 + n * 16 + l16][half * 8];
      acc[n] = __builtin_amdgcn_mfma_f32_16x16x32_bf16(a, b, acc[n], 0, 0, 0);
    }
    __syncthreads();
  }

#pragma unroll
  for (int n = 0; n < 4; ++n) {
    const int col = n0 + wn * 64 + n * 16 + l16;
    const int rowb = m0 + wm * 16 + half * 4;
#pragma unroll
    for (int r = 0; r < 4; ++r)
      if (rowb + r < M)
        C[(size_t)(rowb + r) * 512 + col] = f2bf(acc[n][r]);
  }
}

// ---------------- fused attention per (qtile, h, b), bf16 in/out ----------
// Qb: bf16 [16*4096][512] in/out (in-place h-slice overwrite)
// Kb/Vb: bf16 [16*77][512], col = h*64 + d
__global__ __launch_bounds__(256) void attn_k(const short* __restrict__ Kb,
                                              const short* __restrict__ Vb,
                                              short* __restrict__ Qb) {
  __shared__ short Vt[64][104];     // V^T [d][key], keys zero-padded 77..103
  __shared__ short Pl[4][16][104];  // per-wave P [q][key]

  const int tid = threadIdx.x;
  const int lane = tid & 63, wid = tid >> 6;
  const int half = lane >> 4, l16 = lane & 15;
  const int qt = blockIdx.x, h = blockIdx.y, b = blockIdx.z;
  const size_t kvbase = ((size_t)b * 77) * 512 + h * 64;

  for (int i = tid; i < 77 * 32; i += 256) {
    int key = i >> 5, dp = (i & 31) * 2;
    int wrd = *(const int*)(Vb + kvbase + (size_t)key * 512 + dp);
    Vt[dp][key] = (short)(wrd & 0xffff);
    Vt[dp + 1][key] = (short)((unsigned)wrd >> 16);
  }
  for (int i = tid; i < 64 * 27; i += 256) {
    int d = i / 27, key = 77 + i % 27;
    Vt[d][key] = 0;
  }
  {
    short4v z = {};
    *(short4v*)&Pl[wid][l16][80 + half * 4] = z;
  }
  __syncthreads();

  const size_t qrow = (size_t)b * 4096 + qt * 64 + wid * 16 + l16;
  const short* qp = Qb + qrow * 512 + h * 64;

  // Q fragment (B operand of sim^T = K . Q^T): col=q=l16, k=d
  bf16x8 qfr[2];
#pragma unroll
  for (int ks = 0; ks < 2; ++ks)
    qfr[ks] = *(const bf16x8*)(qp + ks * 32 + half * 8);

  // sim^T: 5 frags of 16 keys x 16 q
  f32x4 c[5] = {};
#pragma unroll
  for (int f = 0; f < 5; ++f) {
    int key = f * 16 + l16;
#pragma unroll
    for (int ks = 0; ks < 2; ++ks) {
      bf16x8 a = {};
      if (key < 77)
        a = *(const bf16x8*)(Kb + kvbase + (size_t)key * 512 + ks * 32 + half * 8);
      c[f] = __builtin_amdgcn_mfma_f32_16x16x32_bf16(a, qfr[ks], c[f], 0, 0, 0);
    }
  }

  // scale + mask + softmax over keys
  float pv[5][4];
  float mx = -1e30f;
#pragma unroll
  for (int f = 0; f < 5; ++f)
#pragma unroll
    for (int r = 0; r < 4; ++r) {
      int key = f * 16 + half * 4 + r;
      float v = c[f][r] * 0.125f;
      if (key >= 77) v = -1e30f;
      pv[f][r] = v;
      mx = fmaxf(mx, v);
    }
  mx = fmaxf(mx, __shfl_xor(mx, 16));
  mx = fmaxf(mx, __shfl_xor(mx, 32));
  float sum = 0.0f;
#pragma unroll
  for (int f = 0; f < 5; ++f)
#pragma unroll
    for (int r = 0; r < 4; ++r) {
      float e = __expf(pv[f][r] - mx);
      pv[f][r] = e;
      sum += e;
    }
  sum += __shfl_xor(sum, 16);
  sum += __shfl_xor(sum, 32);

#pragma unroll
  for (int f = 0; f < 5; ++f) {
    short4v s = {f2bf(pv[f][0]), f2bf(pv[f][1]), f2bf(pv[f][2]), f2bf(pv[f][3])};
    *(short4v*)&Pl[wid][l16][f * 16 + half * 4] = s;
  }
  __syncthreads();

  // out^T = V^T . P^T
  bf16x8 pb[3];
#pragma unroll
  for (int ks = 0; ks < 3; ++ks)
    pb[ks] = *(const bf16x8*)&Pl[wid][l16][ks * 32 + half * 8];
  f32x4 o[4] = {};
#pragma unroll
  for (int mt = 0; mt < 4; ++mt)
#pragma unroll
    for (int ks = 0; ks < 3; ++ks) {
      bf16x8 a = *(const bf16x8*)&Vt[mt * 16 + l16][ks * 32 + half * 8];
      o[mt] = __builtin_amdgcn_mfma_f32_16x16x32_bf16(a, pb[ks], o[mt], 0, 0, 0);
    }

  const float inv = 1.0f / sum;
  short* op = Qb + qrow * 512 + h * 64;
#pragma unroll
  for (int mt = 0; mt < 4; ++mt) {
    short4v s = {f2bf(o[mt][0] * inv), f2bf(o[mt][1] * inv),
                 f2bf(o[mt][2] * inv), f2bf(o[mt][3] * inv)};
    *(short4v*)(op + mt * 16 + half * 4) = s;
  }
}

extern "C" void kernel_launch(void* const* d_in, const int* in_sizes, int n_in,
                              void* d_out, int out_size, void* d_ws, size_t ws_size,
                              hipStream_t stream) {
  const float* x   = (const float*)d_in[0];
  const float* ctx = (const float*)d_in[1];
  const float* Wq  = (const float*)d_in[2];
  const float* Wk  = (const float*)d_in[3];
  const float* Wv  = (const float*)d_in[4];
  const float* Wo  = (const float*)d_in[5];
  const float* bo  = (const float*)d_in[6];
  float* out = (float*)d_out;

  char* ws = (char*)d_ws;
  size_t off = 0;
  short* wqt  = (short*)(ws + off); off += 512 * 512 * 2;   // 524288
  short* wkt  = (short*)(ws + off); off += 768 * 512 * 2;   // 786432
  short* wvt  = (short*)(ws + off); off += 768 * 512 * 2;
  short* wot  = (short*)(ws + off); off += 512 * 512 * 2;
  short* Kb   = (short*)(ws + off); off += 1232 * 512 * 2;  // 1261568
  short* Vb   = (short*)(ws + off); off += 1232 * 512 * 2;
  short* ctxb = (short*)(ws + off); off += (size_t)16 * 77 * 768 * 2;
  short* xb   = (short*)(ws + off); off += (size_t)65536 * 512 * 2;
  short* Qb   = (short*)(ws + off); off += (size_t)65536 * 512 * 2;

  // inputs -> bf16
  conv_bf16<<<2048, 256, 0, stream>>>(x, xb, (size_t)65536 * 512 / 8);
  conv_bf16<<<512, 256, 0, stream>>>(ctx, ctxb, (size_t)16 * 77 * 768 / 8);

  // weights -> bf16 transposed [N][K]
  wt_conv<<<dim3(8, 8), 256, 0, stream>>>(Wq, wqt, 512, 512);
  wt_conv<<<dim3(8, 12), 256, 0, stream>>>(Wk, wkt, 768, 512);
  wt_conv<<<dim3(8, 12), 256, 0, stream>>>(Wv, wvt, 768, 512);
  wt_conv<<<dim3(8, 8), 256, 0, stream>>>(Wo, wot, 512, 512);

  // K/V projections (M=1232, K=768) -> bf16
  gemm_small<<<dim3(4, 39), 256, 0, stream>>>(ctxb, wkt, Kb, 1232, 768);
  gemm_small<<<dim3(4, 39), 256, 0, stream>>>(ctxb, wvt, Vb, 1232, 768);

  // Q projection (65536x512x512) -> bf16 Qb
  gemm_m97<0><<<dim3(4, 512), 256, 0, stream>>>(xb, wqt, Qb, nullptr, 65536, 512, 512);

  // attention, in-place on Qb
  attn_k<<<dim3(64, 8, 16), 256, 0, stream>>>(Kb, Vb, Qb);

  // output projection + bias (65536x512x512) -> f32 d_out
  gemm_m97<2><<<dim3(4, 512), 256, 0, stream>>>(Qb, wot, out, bo, 65536, 512, 512);
}

// Round 3
// 263.540 us; speedup vs baseline: 1.8258x; 1.1562x over previous
//
#include <hip/hip_runtime.h>
#include <hip/hip_bf16.h>
#include <stdint.h>

// CrossAttention: out = softmax((x@Wq)(ctx@Wk)^T * scale) @ (ctx@Wv) @ Wo + bo
// B=16, NQ=4096, NK=77, QD=512, CD=768, H=8, DH=64, INNER=512
//
// Round 2: attn rewrite (pre-transposed V^T global, K staged in LDS,
// 128 q/block, conflict-free strides) + XCD swizzle on the big GEMMs.

typedef __attribute__((ext_vector_type(8))) short bf16x8;
typedef __attribute__((ext_vector_type(4))) float f32x4;
typedef __attribute__((ext_vector_type(4))) short short4v;
typedef __attribute__((ext_vector_type(4))) float float4v;

#define DEVINL __device__ __forceinline__

DEVINL short f2bf(float f) {
  unsigned u = __builtin_bit_cast(unsigned, f);
  unsigned r = (u + 0x7FFFu + ((u >> 16) & 1u)) >> 16;  // RNE
  return (short)(unsigned short)r;
}

#define GLDS16(gp, sp)                                                \
  __builtin_amdgcn_global_load_lds(                                   \
      (const __attribute__((address_space(1))) void*)(gp),            \
      (__attribute__((address_space(3))) void*)(sp), 16, 0, 0)

// ---------------- zero fill (float4 granules) ------------------------------
__global__ __launch_bounds__(256) void fill0(float4v* __restrict__ p, int n4) {
  int i = blockIdx.x * 256 + threadIdx.x;
  if (i < n4) p[i] = float4v{0.f, 0.f, 0.f, 0.f};
}

// ---------------- f32 -> bf16 vectorized convert ---------------------------
__global__ __launch_bounds__(256) void conv_bf16(const float* __restrict__ in,
                                                 short* __restrict__ out,
                                                 size_t n8) {
  size_t i = (size_t)blockIdx.x * 256 + threadIdx.x;
  const size_t stride = (size_t)gridDim.x * 256;
  for (; i < n8; i += stride) {
    float4v a = *(const float4v*)(in + i * 8);
    float4v b = *(const float4v*)(in + i * 8 + 4);
    bf16x8 o = {f2bf(a[0]), f2bf(a[1]), f2bf(a[2]), f2bf(a[3]),
                f2bf(b[0]), f2bf(b[1]), f2bf(b[2]), f2bf(b[3])};
    *(bf16x8*)(out + i * 8) = o;
  }
}

// ---------------- weight transpose+convert: W[K][N] f32 -> Wt[N][K] bf16 ----
__global__ __launch_bounds__(256) void wt_conv(const float* __restrict__ W,
                                               short* __restrict__ Wt,
                                               int K, int N) {
  __shared__ short Tl[64][65];
  const int kt = blockIdx.y * 64, nt = blockIdx.x * 64;
#pragma unroll
  for (int i = 0; i < 16; ++i) {
    int idx = threadIdx.x + i * 256;
    int r = idx >> 6, c = idx & 63;
    Tl[c][r] = f2bf(W[(size_t)(kt + r) * N + nt + c]);
  }
  __syncthreads();
#pragma unroll
  for (int i = 0; i < 16; ++i) {
    int idx = threadIdx.x + i * 256;
    int r = idx >> 6, c = idx & 63;
    Wt[(size_t)(nt + r) * K + kt + c] = Tl[r][c];
  }
}

// ---------------- m97-structure GEMM + XCD swizzle --------------------------
// C[M][N] = A[M][K] @ Bt[N][K]^T, bf16 in. 128x128 tile, BK=64, 4 waves.
// 1-D grid = (M/128)*(N/128), must be %8==0. OUT: 0=bf16, 2=f32+bias.
template <int OUT>
__global__ __launch_bounds__(256) void gemm_m97(const short* __restrict__ A,
                                                const short* __restrict__ Bt,
                                                void* __restrict__ Cv,
                                                const float* __restrict__ bias,
                                                int M, int N, int K) {
  __shared__ short Al[128 * 64];
  __shared__ short Bl[128 * 64];

  const int tid = threadIdx.x;
  const int lane = tid & 63, w = tid >> 6;
  const int wm = w >> 1, wn = w & 1;
  const int quad = lane >> 4, l16 = lane & 15;

  // XCD-chunked swizzle: HW round-robins blockIdx%8 across XCDs; give each
  // XCD a contiguous chunk so blocks sharing an A-panel share an L2.
  const int nwg = gridDim.x;
  const int cpx = nwg >> 3;
  const int wg = blockIdx.x;
  const int swz = (wg & 7) * cpx + (wg >> 3);
  const int nnt = N >> 7;
  const int m0 = (swz / nnt) * 128, n0 = (swz % nnt) * 128;

  const int lr = lane >> 3;       // row within 8-row staging chunk
  const int lc = (lane & 7) * 8;  // bf16 col offset within BK=64

  f32x4 acc[4][4] = {};

  for (int k0 = 0; k0 < K; k0 += 64) {
#pragma unroll
    for (int p = 0; p < 4; ++p) {
      const int row = w * 32 + p * 8;
      GLDS16(A + (size_t)(m0 + row + lr) * K + k0 + lc, &Al[row * 64]);
      GLDS16(Bt + (size_t)(n0 + row + lr) * K + k0 + lc, &Bl[row * 64]);
    }
    __syncthreads();

#pragma unroll
    for (int ks = 0; ks < 2; ++ks) {
      bf16x8 af[4], bfr[4];
#pragma unroll
      for (int m = 0; m < 4; ++m)
        af[m] = *(bf16x8*)&Al[(wm * 64 + m * 16 + l16) * 64 + ks * 32 + quad * 8];
#pragma unroll
      for (int n = 0; n < 4; ++n)
        bfr[n] = *(bf16x8*)&Bl[(wn * 64 + n * 16 + l16) * 64 + ks * 32 + quad * 8];
#pragma unroll
      for (int m = 0; m < 4; ++m)
#pragma unroll
        for (int n = 0; n < 4; ++n)
          acc[m][n] = __builtin_amdgcn_mfma_f32_16x16x32_bf16(af[m], bfr[n],
                                                              acc[m][n], 0, 0, 0);
    }
    __syncthreads();
  }

#pragma unroll
  for (int m = 0; m < 4; ++m) {
#pragma unroll
    for (int n = 0; n < 4; ++n) {
      const int col = n0 + wn * 64 + n * 16 + l16;
      const int rowb = m0 + wm * 64 + m * 16 + quad * 4;
      const float badd = (OUT == 2) ? bias[col] : 0.0f;
#pragma unroll
      for (int r = 0; r < 4; ++r) {
        if constexpr (OUT == 0)
          ((short*)Cv)[(size_t)(rowb + r) * N + col] = f2bf(acc[m][n][r]);
        else
          ((float*)Cv)[(size_t)(rowb + r) * N + col] = acc[m][n][r] + badd;
      }
    }
  }
}

// ---------------- small GEMM (f32 A): C = A[M][K]f32 @ Bt[512][K]^T ---------
// TRANS=0: bf16 C[M][512].  TRANS=1: scatter to Vtg[((b*8+h)*64+d)*104+key].
template <int TRANS>
__global__ __launch_bounds__(256) void gemm_small(const float* __restrict__ A,
                                                  const short* __restrict__ Bt,
                                                  short* __restrict__ C,
                                                  int M, int K) {
  __shared__ short Al[32][40];
  __shared__ short Bl[128][40];

  const int tid = threadIdx.x;
  const int lane = tid & 63, wid = tid >> 6;
  const int wm = wid >> 1, wn = wid & 1;
  const int quad = lane >> 4, l16 = lane & 15;
  const int m0 = blockIdx.y * 32, n0 = blockIdx.x * 128;

  f32x4 acc[4] = {};

  for (int k0 = 0; k0 < K; k0 += 32) {
    for (int idx = tid; idx < 32 * 8; idx += 256) {
      int row = idx >> 3, kq = idx & 7;
      float4v v = {};
      if (m0 + row < M)
        v = *(const float4v*)(A + (size_t)(m0 + row) * K + k0 + kq * 4);
      short4v s = {f2bf(v[0]), f2bf(v[1]), f2bf(v[2]), f2bf(v[3])};
      *(short4v*)&Al[row][kq * 4] = s;
    }
    for (int idx = tid; idx < 512; idx += 256) {
      int row = idx >> 2, kq = idx & 3;
      *(bf16x8*)&Bl[row][kq * 8] =
          *(const bf16x8*)(Bt + (size_t)(n0 + row) * K + k0 + kq * 8);
    }
    __syncthreads();

    bf16x8 a = *(bf16x8*)&Al[wm * 16 + l16][quad * 8];
#pragma unroll
    for (int n = 0; n < 4; ++n) {
      bf16x8 b = *(bf16x8*)&Bl[wn * 64 + n * 16 + l16][quad * 8];
      acc[n] = __builtin_amdgcn_mfma_f32_16x16x32_bf16(a, b, acc[n], 0, 0, 0);
    }
    __syncthreads();
  }

#pragma unroll
  for (int n = 0; n < 4; ++n) {
    const int col = n0 + wn * 64 + n * 16 + l16;
    const int rowb = m0 + wm * 16 + quad * 4;
#pragma unroll
    for (int r = 0; r < 4; ++r) {
      const int rr = rowb + r;
      if (rr < M) {
        if constexpr (TRANS == 0) {
          C[(size_t)rr * 512 + col] = f2bf(acc[n][r]);
        } else {
          const int bb = rr / 77, key = rr - bb * 77;
          C[(size_t)((bb * 8 + (col >> 6)) * 64 + (col & 63)) * 104 + key] =
              f2bf(acc[n][r]);
        }
      }
    }
  }
}

// ---------------- fused attention: 128 q rows x 1 head per block -----------
// Kb: bf16 [16*77][512] (col=h*64+d); Vtg: bf16 [16][8][64][104] (padded V^T)
// Qb: bf16 [65536][512] in/out
__global__ __launch_bounds__(256) void attn2(const short* __restrict__ Kb,
                                             const short* __restrict__ Vtg,
                                             short* __restrict__ Qb) {
  __shared__ short Kl[80 * 72];    // K [key][d], stride 72 (2-way banks)
  __shared__ short Vt[64 * 104];   // V^T [d][key], stride 104 (2-way)
  __shared__ short Pl[128 * 104];  // P [q][key]

  const int tid = threadIdx.x;
  const int lane = tid & 63, wid = tid >> 6;
  const int quad = lane >> 4, l16 = lane & 15;
  const int qt = blockIdx.x, h = blockIdx.y, b = blockIdx.z;

  const size_t kbase = (size_t)b * 77 * 512 + h * 64;
  const size_t vbase = (size_t)(b * 8 + h) * 64 * 104;

  // zero P pad cols 80..95 (all 128 rows)
  {
    bf16x8 z = {};
    *(bf16x8*)&Pl[(tid >> 1) * 104 + 80 + (tid & 1) * 8] = z;
  }
  // stage K rows 0..76 (rows 77..79 garbage -> masked in softmax)
  for (int idx = tid; idx < 616; idx += 256) {
    int row = idx >> 3, c = idx & 7;
    *(bf16x8*)&Kl[row * 72 + c * 8] =
        *(const bf16x8*)(Kb + kbase + (size_t)row * 512 + c * 8);
  }
  // stage V^T linearly (global layout == LDS layout) via global_load_lds
#pragma unroll
  for (int it = 0; it < 4; ++it) {
    int cb = it * 256 + wid * 64;  // wave-uniform 16B-chunk base
    if (cb < 832) GLDS16(Vtg + vbase + (size_t)(cb + lane) * 8, &Vt[cb * 8]);
  }
  __syncthreads();

  const int qb0 = qt * 128 + wid * 32;

  // Q fragments for 2 q-tiles (B operand: col=q=l16, k=d)
  size_t qrow[2];
  bf16x8 qfr[2][2];
#pragma unroll
  for (int t = 0; t < 2; ++t) {
    qrow[t] = (size_t)b * 4096 + qb0 + t * 16 + l16;
    const short* qp = Qb + qrow[t] * 512 + h * 64;
#pragma unroll
    for (int ks = 0; ks < 2; ++ks)
      qfr[t][ks] = *(const bf16x8*)(qp + ks * 32 + quad * 8);
  }

  // sim^T = K . Q^T : c[f][t][r] = sim[key=f*16+quad*4+r][q=l16]
  f32x4 c[5][2] = {};
#pragma unroll
  for (int f = 0; f < 5; ++f)
#pragma unroll
    for (int ks = 0; ks < 2; ++ks) {
      bf16x8 a = *(bf16x8*)&Kl[(f * 16 + l16) * 72 + ks * 32 + quad * 8];
      c[f][0] = __builtin_amdgcn_mfma_f32_16x16x32_bf16(a, qfr[0][ks], c[f][0], 0, 0, 0);
      c[f][1] = __builtin_amdgcn_mfma_f32_16x16x32_bf16(a, qfr[1][ks], c[f][1], 0, 0, 0);
    }

  // softmax over keys (4 lanes per q-column: quads), write P (unnormalized)
  float inv[2];
#pragma unroll
  for (int t = 0; t < 2; ++t) {
    float mx = -1e30f;
#pragma unroll
    for (int f = 0; f < 5; ++f)
#pragma unroll
      for (int r = 0; r < 4; ++r) {
        int key = f * 16 + quad * 4 + r;
        float v = c[f][t][r] * 0.125f;
        v = (key < 77) ? v : -1e30f;
        c[f][t][r] = v;
        mx = fmaxf(mx, v);
      }
    mx = fmaxf(mx, __shfl_xor(mx, 16));
    mx = fmaxf(mx, __shfl_xor(mx, 32));
    float sum = 0.f;
#pragma unroll
    for (int f = 0; f < 5; ++f) {
#pragma unroll
      for (int r = 0; r < 4; ++r) {
        float e = __expf(c[f][t][r] - mx);
        c[f][t][r] = e;
        sum += e;
      }
      short4v s = {f2bf(c[f][t][0]), f2bf(c[f][t][1]),
                   f2bf(c[f][t][2]), f2bf(c[f][t][3])};
      *(short4v*)&Pl[(wid * 32 + t * 16 + l16) * 104 + f * 16 + quad * 4] = s;
    }
    sum += __shfl_xor(sum, 16);
    sum += __shfl_xor(sum, 32);
    inv[t] = 1.0f / sum;
  }
  __syncthreads();  // P visible (cross-lane within wave; also reconverges)

  // out^T = V^T . P^T
  bf16x8 pb[2][3];
#pragma unroll
  for (int t = 0; t < 2; ++t)
#pragma unroll
    for (int ks = 0; ks < 3; ++ks)
      pb[t][ks] = *(bf16x8*)&Pl[(wid * 32 + t * 16 + l16) * 104 + ks * 32 + quad * 8];

  f32x4 o[4][2] = {};
#pragma unroll
  for (int mt = 0; mt < 4; ++mt)
#pragma unroll
    for (int ks = 0; ks < 3; ++ks) {
      bf16x8 a = *(bf16x8*)&Vt[(mt * 16 + l16) * 104 + ks * 32 + quad * 8];
      o[mt][0] = __builtin_amdgcn_mfma_f32_16x16x32_bf16(a, pb[0][ks], o[mt][0], 0, 0, 0);
      o[mt][1] = __builtin_amdgcn_mfma_f32_16x16x32_bf16(a, pb[1][ks], o[mt][1], 0, 0, 0);
    }

#pragma unroll
  for (int t = 0; t < 2; ++t) {
    short* op = Qb + qrow[t] * 512 + h * 64;
#pragma unroll
    for (int mt = 0; mt < 4; ++mt) {
      short4v s = {f2bf(o[mt][t][0] * inv[t]), f2bf(o[mt][t][1] * inv[t]),
                   f2bf(o[mt][t][2] * inv[t]), f2bf(o[mt][t][3] * inv[t])};
      *(short4v*)(op + mt * 16 + quad * 4) = s;
    }
  }
}

extern "C" void kernel_launch(void* const* d_in, const int* in_sizes, int n_in,
                              void* d_out, int out_size, void* d_ws, size_t ws_size,
                              hipStream_t stream) {
  const float* x   = (const float*)d_in[0];
  const float* ctx = (const float*)d_in[1];
  const float* Wq  = (const float*)d_in[2];
  const float* Wk  = (const float*)d_in[3];
  const float* Wv  = (const float*)d_in[4];
  const float* Wo  = (const float*)d_in[5];
  const float* bo  = (const float*)d_in[6];
  float* out = (float*)d_out;

  char* ws = (char*)d_ws;
  size_t off = 0;
  short* wqt = (short*)(ws + off); off += 512 * 512 * 2;
  short* wkt = (short*)(ws + off); off += 768 * 512 * 2;
  short* wvt = (short*)(ws + off); off += 768 * 512 * 2;
  short* wot = (short*)(ws + off); off += 512 * 512 * 2;
  short* Kb  = (short*)(ws + off); off += 1232 * 512 * 2;
  short* Vtg = (short*)(ws + off); off += (size_t)16 * 8 * 64 * 104 * 2;
  short* xb  = (short*)(ws + off); off += (size_t)65536 * 512 * 2;
  short* Qb  = (short*)(ws + off); off += (size_t)65536 * 512 * 2;

  // x -> bf16
  conv_bf16<<<2048, 256, 0, stream>>>(x, xb, (size_t)65536 * 512 / 8);

  // weights -> bf16 transposed [N][K]
  wt_conv<<<dim3(8, 8), 256, 0, stream>>>(Wq, wqt, 512, 512);
  wt_conv<<<dim3(8, 12), 256, 0, stream>>>(Wk, wkt, 768, 512);
  wt_conv<<<dim3(8, 12), 256, 0, stream>>>(Wv, wvt, 768, 512);
  wt_conv<<<dim3(8, 8), 256, 0, stream>>>(Wo, wot, 512, 512);

  // zero-fill Vtg (pads must be 0), then K/V projections from f32 ctx
  fill0<<<416, 256, 0, stream>>>((float4v*)Vtg, 106496);
  gemm_small<0><<<dim3(4, 39), 256, 0, stream>>>(ctx, wkt, Kb, 1232, 768);
  gemm_small<1><<<dim3(4, 39), 256, 0, stream>>>(ctx, wvt, Vtg, 1232, 768);

  // Q projection (65536x512x512) -> bf16 Qb
  gemm_m97<0><<<2048, 256, 0, stream>>>(xb, wqt, Qb, nullptr, 65536, 512, 512);

  // attention, in-place on Qb
  attn2<<<dim3(32, 8, 16), 256, 0, stream>>>(Kb, Vtg, Qb);

  // output projection + bias -> f32 d_out
  gemm_m97<2><<<2048, 256, 0, stream>>>(Qb, wot, out, bo, 65536, 512, 512);
}